// Round 1
// baseline (146.722 us; speedup 1.0000x reference)
//
#include <hip/hip_runtime.h>
#include <hip/hip_bf16.h>

#define Bn 8
#define Sn 2048
#define Dn 512
#define Kn 64

typedef _Float16 half8 __attribute__((ext_vector_type(8)));
typedef float f32x4 __attribute__((ext_vector_type(4)));

// ---- LDS helpers: all tiles are [rows][64] f16, 128B rows, XOR-swizzled on
// 16B granules within the row: byte_in_row ^= (row&7)<<4 ----
__device__ __forceinline__ void stage_8kb(_Float16* dst, const _Float16* src, int tid){
    #pragma unroll
    for (int i = 0; i < 2; ++i){
        const int c   = tid + 256*i;
        const int row = c >> 3, col = c & 7;
        const int scol = col ^ (row & 7);
        *(int4*)((char*)dst + row*128 + scol*16) = ((const int4*)src)[c];
    }
}

__device__ __forceinline__ half8 ldfrag(const _Float16* base, int row, int k8){
    const int scol = k8 ^ (row & 7);
    return *(const half8*)((const char*)base + row*128 + scol*16);
}

// ---- Kernel 1: Q/K projection GEMM: [16384 x 512] @ [512 x 128] -> f16 Q,K ----
__global__ __launch_bounds__(256) void qkproj_kernel(
    const float* __restrict__ X, const float* __restrict__ Wk, const float* __restrict__ bk,
    const float* __restrict__ Wq, const float* __restrict__ bq,
    _Float16* __restrict__ Qh, _Float16* __restrict__ Kh)
{
    __shared__ _Float16 Xt[64*64];     // [64 q][64 d-chunk]
    __shared__ _Float16 Wt[128*64];    // [128 n][64 d-chunk]  (n<64 -> Wq col, else Wk col)
    const int q0  = blockIdx.x * 64;   // global row index into (B*S)
    const int tid = threadIdx.x, lane = tid & 63, w = tid >> 6;

    f32x4 acc[4][2];
    #pragma unroll
    for (int i = 0; i < 4; ++i)
        #pragma unroll
        for (int j = 0; j < 2; ++j){ f32x4 z = {0.f,0.f,0.f,0.f}; acc[i][j] = z; }

    for (int kc = 0; kc < Dn/64; ++kc){
        __syncthreads();
        // stage X tile (f32 -> f16, swizzled)
        #pragma unroll
        for (int i = 0; i < 2; ++i){
            const int g = tid + 256*i;
            const int row = g >> 3, col = g & 7;
            const float* s = X + (size_t)(q0 + row)*Dn + kc*64 + col*8;
            const float4 v0 = *(const float4*)s;
            const float4 v1 = *(const float4*)(s + 4);
            half8 h;
            h[0]=(_Float16)v0.x; h[1]=(_Float16)v0.y; h[2]=(_Float16)v0.z; h[3]=(_Float16)v0.w;
            h[4]=(_Float16)v1.x; h[5]=(_Float16)v1.y; h[6]=(_Float16)v1.z; h[7]=(_Float16)v1.w;
            *(half8*)((char*)Xt + row*128 + ((col ^ (row & 7))*16)) = h;
        }
        // stage W tile transposed: Wt[n][k] = W[kc*64+k][n]
        {
            const int n  = tid >> 1;
            const int kb = (tid & 1) * 32;
            const float* Wsrc = (n < 64) ? Wq : Wk;
            const int nn = n & 63;
            #pragma unroll
            for (int j = 0; j < 32; ++j){
                const int k = kb + j;
                const float v = Wsrc[(size_t)(kc*64 + k)*Kn + nn];
                *(_Float16*)((char*)Wt + n*128 + ((k*2) ^ ((n & 7) << 4))) = (_Float16)v;
            }
        }
        __syncthreads();
        #pragma unroll
        for (int ks = 0; ks < 2; ++ks){
            half8 a[4];
            #pragma unroll
            for (int qt = 0; qt < 4; ++qt)
                a[qt] = ldfrag(Xt, qt*16 + (lane & 15), ks*4 + (lane >> 4));
            #pragma unroll
            for (int nt = 0; nt < 2; ++nt){
                const half8 bfr = ldfrag(Wt, w*32 + nt*16 + (lane & 15), ks*4 + (lane >> 4));
                #pragma unroll
                for (int qt = 0; qt < 4; ++qt)
                    acc[qt][nt] = __builtin_amdgcn_mfma_f32_16x16x32_f16(a[qt], bfr, acc[qt][nt], 0, 0, 0);
            }
        }
    }
    // epilogue: bias + cast + store
    #pragma unroll
    for (int qt = 0; qt < 4; ++qt){
        const int row = q0 + qt*16 + (lane >> 4)*4;
        #pragma unroll
        for (int nt = 0; nt < 2; ++nt){
            const int n = w*32 + nt*16 + (lane & 15);
            const float bias = (n < 64) ? bq[n] : bk[n - 64];
            #pragma unroll
            for (int r = 0; r < 4; ++r){
                const float v = acc[qt][nt][r] + bias;
                if (n < 64) Qh[(size_t)(row + r)*Kn + n]        = (_Float16)v;
                else        Kh[(size_t)(row + r)*Kn + (n - 64)] = (_Float16)v;
            }
        }
    }
}

// ---- Kernel 2: V transpose + cast: Vt[b][d][s] = (f16)X[b][s][d] ----
__global__ __launch_bounds__(256) void transpose_kernel(
    const float* __restrict__ X, _Float16* __restrict__ Vt)
{
    __shared__ _Float16 tile[64*66];
    const int bid = blockIdx.x;
    const int b  = bid >> 8;
    const int s0 = ((bid >> 3) & 31) * 64;
    const int d0 = (bid & 7) * 64;
    const int tid = threadIdx.x;
    #pragma unroll
    for (int i = 0; i < 4; ++i){
        const int sl = (tid >> 4) + i*16;
        const int dl = (tid & 15) * 4;
        const float4 v = *(const float4*)(X + ((size_t)(b*Sn + s0 + sl))*Dn + d0 + dl);
        tile[(dl+0)*66 + sl] = (_Float16)v.x;
        tile[(dl+1)*66 + sl] = (_Float16)v.y;
        tile[(dl+2)*66 + sl] = (_Float16)v.z;
        tile[(dl+3)*66 + sl] = (_Float16)v.w;
    }
    __syncthreads();
    const int dl = tid >> 2;
    const int sl = (tid & 3) * 16;
    const unsigned* tp = (const unsigned*)&tile[dl*66 + sl];
    uint4 o0, o1;
    o0.x = tp[0]; o0.y = tp[1]; o0.z = tp[2]; o0.w = tp[3];
    o1.x = tp[4]; o1.y = tp[5]; o1.z = tp[6]; o1.w = tp[7];
    _Float16* dst = Vt + ((size_t)(b*Dn + d0 + dl))*Sn + s0 + sl;
    *(uint4*)dst = o0;
    *(uint4*)(dst + 8) = o1;
}

// ---- Kernel 3: per-(b,s) column stats over q: m = max_q logits, invZ ----
__global__ __launch_bounds__(256) void stats_kernel(
    const _Float16* __restrict__ Qh, const _Float16* __restrict__ Kh,
    float* __restrict__ Ms, float* __restrict__ IZ)
{
    __shared__ _Float16 Kt[64*64];
    __shared__ _Float16 Qt[64*64];
    const int b  = blockIdx.x >> 5;
    const int st = blockIdx.x & 31;
    const int tid = threadIdx.x, lane = tid & 63, w = tid >> 6;
    stage_8kb(Kt, Kh + ((size_t)(b*Sn + st*64))*Kn, tid);
    __syncthreads();
    const int srow = w*16 + (lane & 15);
    const half8 kb0 = ldfrag(Kt, srow, lane >> 4);
    const half8 kb1 = ldfrag(Kt, srow, 4 + (lane >> 4));
    float m_run = -3.0e38f, Z = 0.f;
    for (int qc = 0; qc < Sn/64; ++qc){
        __syncthreads();
        stage_8kb(Qt, Qh + ((size_t)(b*Sn + qc*64))*Kn, tid);
        __syncthreads();
        f32x4 acc[4];
        float cmax = -3.0e38f;
        #pragma unroll
        for (int qt = 0; qt < 4; ++qt){
            const half8 a0 = ldfrag(Qt, qt*16 + (lane & 15), lane >> 4);
            const half8 a1 = ldfrag(Qt, qt*16 + (lane & 15), 4 + (lane >> 4));
            f32x4 c = {0.f,0.f,0.f,0.f};
            c = __builtin_amdgcn_mfma_f32_16x16x32_f16(a0, kb0, c, 0, 0, 0);
            c = __builtin_amdgcn_mfma_f32_16x16x32_f16(a1, kb1, c, 0, 0, 0);
            acc[qt] = c;
            cmax = fmaxf(cmax, fmaxf(fmaxf(c[0], c[1]), fmaxf(c[2], c[3])));
        }
        cmax = fmaxf(cmax, __shfl_xor(cmax, 16));
        cmax = fmaxf(cmax, __shfl_xor(cmax, 32));
        const float m_new = fmaxf(m_run, cmax);
        float zc = 0.f;
        #pragma unroll
        for (int qt = 0; qt < 4; ++qt)
            #pragma unroll
            for (int r = 0; r < 4; ++r)
                zc += __expf(acc[qt][r] - m_new);
        zc += __shfl_xor(zc, 16);
        zc += __shfl_xor(zc, 32);
        Z = Z * __expf(m_run - m_new) + zc;
        m_run = m_new;
    }
    if (lane < 16){
        const int s = st*64 + w*16 + lane;
        Ms[b*Sn + s] = m_run;
        IZ[b*Sn + s] = 1.0f / Z;
    }
}

// ---- Kernel 4: fused logits -> P -> P@V ----
__global__ __launch_bounds__(256) void attn_kernel(
    const _Float16* __restrict__ Qh, const _Float16* __restrict__ Kh,
    const _Float16* __restrict__ Vt, const float* __restrict__ Ms,
    const float* __restrict__ IZ, float* __restrict__ out)
{
    __shared__ _Float16 Qt[64*64];
    __shared__ _Float16 Kt[64*64];
    __shared__ _Float16 Pt[64*64];
    __shared__ _Float16 Vts[256*64];
    const int bid = blockIdx.x;
    const int b  = bid >> 6;
    const int qi = (bid >> 1) & 31;
    const int di = bid & 1;
    const int q0 = qi * 64;
    const int dbase = di * 256;
    const int tid = threadIdx.x, lane = tid & 63, w = tid >> 6;
    const int bS = b * Sn;

    stage_8kb(Qt, Qh + ((size_t)(bS + q0))*Kn, tid);
    __syncthreads();
    const half8 qa0 = ldfrag(Qt, w*16 + (lane & 15), lane >> 4);
    const half8 qa1 = ldfrag(Qt, w*16 + (lane & 15), 4 + (lane >> 4));

    f32x4 acc[4][4];
    #pragma unroll
    for (int i = 0; i < 4; ++i)
        #pragma unroll
        for (int j = 0; j < 4; ++j){ f32x4 z = {0.f,0.f,0.f,0.f}; acc[i][j] = z; }

    for (int sc = 0; sc < Sn/64; ++sc){
        __syncthreads();
        stage_8kb(Kt, Kh + ((size_t)(bS + sc*64))*Kn, tid);
        #pragma unroll
        for (int i = 0; i < 8; ++i){
            const int c = tid + 256*i;
            const int row = c >> 3, col = c & 7;
            const int scol = col ^ (row & 7);
            const int4 v = *(const int4*)(Vt + ((size_t)(b*Dn + dbase + row))*Sn + sc*64 + col*8);
            *(int4*)((char*)Vts + row*128 + scol*16) = v;
        }
        __syncthreads();
        // logits + P (wave w does q rows [w*16, w*16+16) x all 64 s)
        #pragma unroll
        for (int st4 = 0; st4 < 4; ++st4){
            const int srowl = st4*16 + (lane & 15);
            const half8 b0 = ldfrag(Kt, srowl, lane >> 4);
            const half8 b1 = ldfrag(Kt, srowl, 4 + (lane >> 4));
            f32x4 c = {0.f,0.f,0.f,0.f};
            c = __builtin_amdgcn_mfma_f32_16x16x32_f16(qa0, b0, c, 0, 0, 0);
            c = __builtin_amdgcn_mfma_f32_16x16x32_f16(qa1, b1, c, 0, 0, 0);
            const int scol = sc*64 + st4*16 + (lane & 15);
            const float mm = Ms[bS + scol];
            const float zz = IZ[bS + scol];
            const int qrow = w*16 + (lane >> 4)*4;
            #pragma unroll
            for (int r = 0; r < 4; ++r){
                const float p = __expf(c[r] - mm) * zz;
                const int byteoff = ((st4*16 + (lane & 15))*2) ^ (((qrow + r) & 7) << 4);
                *(_Float16*)((char*)Pt + (qrow + r)*128 + byteoff) = (_Float16)p;
            }
        }
        __syncthreads();
        // PV: wave w owns d slice [w*64, w*64+64)
        #pragma unroll
        for (int ks = 0; ks < 2; ++ks){
            half8 pa[4];
            #pragma unroll
            for (int qt4 = 0; qt4 < 4; ++qt4)
                pa[qt4] = ldfrag(Pt, qt4*16 + (lane & 15), ks*4 + (lane >> 4));
            #pragma unroll
            for (int dt4 = 0; dt4 < 4; ++dt4){
                const half8 vb = ldfrag(Vts, w*64 + dt4*16 + (lane & 15), ks*4 + (lane >> 4));
                #pragma unroll
                for (int qt4 = 0; qt4 < 4; ++qt4)
                    acc[qt4][dt4] = __builtin_amdgcn_mfma_f32_16x16x32_f16(pa[qt4], vb, acc[qt4][dt4], 0, 0, 0);
            }
        }
    }
    // epilogue
    #pragma unroll
    for (int qt4 = 0; qt4 < 4; ++qt4){
        const int q = q0 + qt4*16 + (lane >> 4)*4;
        #pragma unroll
        for (int dt4 = 0; dt4 < 4; ++dt4){
            const int d = dbase + w*64 + dt4*16 + (lane & 15);
            #pragma unroll
            for (int r = 0; r < 4; ++r)
                out[((size_t)(bS + q + r))*Dn + d] = acc[qt4][dt4][r];
        }
    }
}

extern "C" void kernel_launch(void* const* d_in, const int* in_sizes, int n_in,
                              void* d_out, int out_size, void* d_ws, size_t ws_size,
                              hipStream_t stream)
{
    const float* X  = (const float*)d_in[0];
    const float* Wk = (const float*)d_in[1];
    const float* bk = (const float*)d_in[2];
    const float* Wq = (const float*)d_in[3];
    const float* bq = (const float*)d_in[4];
    float* out = (float*)d_out;

    char* ws = (char*)d_ws;
    _Float16* Qh = (_Float16*)ws;                               // 2 MB
    _Float16* Kh = (_Float16*)(ws + ((size_t)2 << 20));         // 2 MB
    _Float16* Vt = (_Float16*)(ws + ((size_t)4 << 20));         // 16 MB
    float*    Ms = (float*)(ws + ((size_t)20 << 20));           // 64 KB
    float*    IZ = (float*)(ws + ((size_t)20 << 20) + (1 << 16)); // 64 KB

    qkproj_kernel<<<dim3((Bn*Sn)/64), dim3(256), 0, stream>>>(X, Wk, bk, Wq, bq, Qh, Kh);
    transpose_kernel<<<dim3(Bn*(Sn/64)*(Dn/64)), dim3(256), 0, stream>>>(X, Vt);
    stats_kernel<<<dim3(Bn*(Sn/64)), dim3(256), 0, stream>>>(Qh, Kh, Ms, IZ);
    attn_kernel<<<dim3(Bn*(Sn/64)*(Dn/256)), dim3(256), 0, stream>>>(Qh, Kh, Vt, Ms, IZ, out);
}

// Round 2
// 114.214 us; speedup vs baseline: 1.2846x; 1.2846x over previous
//
#include <hip/hip_runtime.h>
#include <hip/hip_bf16.h>

#define Bn 8
#define Sn 2048
#define Dn 512
#define Kn 64

typedef _Float16 half8 __attribute__((ext_vector_type(8)));
typedef _Float16 half4v __attribute__((ext_vector_type(4)));
typedef float f32x4 __attribute__((ext_vector_type(4)));

// async global->LDS, 16B per lane; LDS dest is wave-uniform base + lane*16
__device__ __forceinline__ void glds16(const void* g, void* l){
    __builtin_amdgcn_global_load_lds(
        (const __attribute__((address_space(1))) unsigned int*)g,
        (__attribute__((address_space(3))) unsigned int*)l, 16, 0, 0);
}

// All LDS tiles are [rows][64] f16 (128B rows), XOR-swizzled on 16B granules:
// phys granule = logical granule ^ (row&7). Staging pre-applies the same
// involution on the global source so LDS writes stay linear (global_load_lds).
__device__ __forceinline__ half8 ldfrag(const _Float16* base, int row, int k8){
    const int scol = k8 ^ (row & 7);
    return *(const half8*)((const char*)base + row*128 + scol*16);
}

// ---- Kernel 0: W transpose+cast: Wt16[n][k], n<64 -> Wq col n, else Wk ----
__global__ __launch_bounds__(256) void wtrans_kernel(
    const float* __restrict__ Wk, const float* __restrict__ Wq,
    _Float16* __restrict__ Wt16)
{
    const int n = blockIdx.x;          // 0..127
    const int t = threadIdx.x;
    const float* src = (n < 64) ? Wq : Wk;
    const int nn = n & 63;
    #pragma unroll
    for (int i = 0; i < 2; ++i){
        const int k = t + 256*i;
        Wt16[(size_t)n*Dn + k] = (_Float16)src[(size_t)k*Kn + nn];
    }
}

// ---- Kernel 1: Q/K projection GEMM: [16384 x 512] @ [512 x 128] -> f16 ----
__global__ __launch_bounds__(256) void qkproj_kernel(
    const float* __restrict__ X, const _Float16* __restrict__ Wt16,
    const float* __restrict__ bk, const float* __restrict__ bq,
    _Float16* __restrict__ Qh, _Float16* __restrict__ Kh)
{
    __shared__ _Float16 Xt[64*64];
    __shared__ _Float16 Wt[128*64];
    const int q0  = blockIdx.x * 64;
    const int tid = threadIdx.x, lane = tid & 63, w = tid >> 6;

    f32x4 acc[4][2];
    #pragma unroll
    for (int i = 0; i < 4; ++i)
        #pragma unroll
        for (int j = 0; j < 2; ++j){ f32x4 z = {0.f,0.f,0.f,0.f}; acc[i][j] = z; }

    for (int kc = 0; kc < Dn/64; ++kc){
        __syncthreads();
        // W tile [128 n][64 k] via global_load_lds (pre-swizzled source)
        #pragma unroll
        for (int i = 0; i < 4; ++i){
            const int c  = tid + 256*i;
            const int rw = c >> 3, cw = c & 7;
            glds16((const char*)Wt16 + (size_t)rw*1024 + kc*128 + ((cw ^ (rw & 7))*16),
                   (char*)Wt + w*1024 + i*4096);
        }
        // X tile (f32 -> f16, swizzled store)
        #pragma unroll
        for (int i = 0; i < 2; ++i){
            const int g = tid + 256*i;
            const int row = g >> 3, col = g & 7;
            const float* s = X + (size_t)(q0 + row)*Dn + kc*64 + col*8;
            const float4 v0 = *(const float4*)s;
            const float4 v1 = *(const float4*)(s + 4);
            half8 h;
            h[0]=(_Float16)v0.x; h[1]=(_Float16)v0.y; h[2]=(_Float16)v0.z; h[3]=(_Float16)v0.w;
            h[4]=(_Float16)v1.x; h[5]=(_Float16)v1.y; h[6]=(_Float16)v1.z; h[7]=(_Float16)v1.w;
            *(half8*)((char*)Xt + row*128 + ((col ^ (row & 7))*16)) = h;
        }
        __syncthreads();
        #pragma unroll
        for (int ks = 0; ks < 2; ++ks){
            half8 a[4];
            #pragma unroll
            for (int qt = 0; qt < 4; ++qt)
                a[qt] = ldfrag(Xt, qt*16 + (lane & 15), ks*4 + (lane >> 4));
            #pragma unroll
            for (int nt = 0; nt < 2; ++nt){
                const half8 bfr = ldfrag(Wt, w*32 + nt*16 + (lane & 15), ks*4 + (lane >> 4));
                #pragma unroll
                for (int qt = 0; qt < 4; ++qt)
                    acc[qt][nt] = __builtin_amdgcn_mfma_f32_16x16x32_f16(a[qt], bfr, acc[qt][nt], 0, 0, 0);
            }
        }
    }
    #pragma unroll
    for (int qt = 0; qt < 4; ++qt){
        const int row = q0 + qt*16 + (lane >> 4)*4;
        #pragma unroll
        for (int nt = 0; nt < 2; ++nt){
            const int n = w*32 + nt*16 + (lane & 15);
            const float bias = (n < 64) ? bq[n] : bk[n - 64];
            #pragma unroll
            for (int r = 0; r < 4; ++r){
                const float v = acc[qt][nt][r] + bias;
                if (n < 64) Qh[(size_t)(row + r)*Kn + n]        = (_Float16)v;
                else        Kh[(size_t)(row + r)*Kn + (n - 64)] = (_Float16)v;
            }
        }
    }
}

// ---- Kernel 2: V transpose + cast: Vt[b][d][s] = (f16)X[b][s][d] ----
__global__ __launch_bounds__(256) void transpose_kernel(
    const float* __restrict__ X, _Float16* __restrict__ Vt)
{
    __shared__ _Float16 tile[64*66];
    const int bid = blockIdx.x;
    const int b  = bid >> 8;
    const int s0 = ((bid >> 3) & 31) * 64;
    const int d0 = (bid & 7) * 64;
    const int tid = threadIdx.x;
    #pragma unroll
    for (int i = 0; i < 4; ++i){
        const int sl = (tid >> 4) + i*16;
        const int dl = (tid & 15) * 4;
        const float4 v = *(const float4*)(X + ((size_t)(b*Sn + s0 + sl))*Dn + d0 + dl);
        tile[(dl+0)*66 + sl] = (_Float16)v.x;
        tile[(dl+1)*66 + sl] = (_Float16)v.y;
        tile[(dl+2)*66 + sl] = (_Float16)v.z;
        tile[(dl+3)*66 + sl] = (_Float16)v.w;
    }
    __syncthreads();
    const int dl = tid >> 2;
    const int sl = (tid & 3) * 16;
    const unsigned* tp = (const unsigned*)&tile[dl*66 + sl];
    uint4 o0, o1;
    o0.x = tp[0]; o0.y = tp[1]; o0.z = tp[2]; o0.w = tp[3];
    o1.x = tp[4]; o1.y = tp[5]; o1.z = tp[6]; o1.w = tp[7];
    _Float16* dst = Vt + ((size_t)(b*Dn + d0 + dl))*Sn + s0 + sl;
    *(uint4*)dst = o0;
    *(uint4*)(dst + 8) = o1;
}

// ---- Kernel 3: per-(b,s) column stats over q (swapped-operand QK) ----
__global__ __launch_bounds__(512, 2) void stats_kernel(
    const _Float16* __restrict__ Qh, const _Float16* __restrict__ Kh,
    float* __restrict__ Ms, float* __restrict__ IZ)
{
    __shared__ _Float16 Kt[64*64];
    __shared__ _Float16 Qt[2][64*64];
    __shared__ float mred[2][64];
    __shared__ float zred[2][64];
    const int bid = blockIdx.x;
    const int b = bid & 7, stb = bid >> 3;       // b-major -> one b per XCD
    const int tid = threadIdx.x, lane = tid & 63, w = tid >> 6;
    const int l15 = lane & 15, l4 = lane >> 4;
    const int sw = w & 3, qh = w >> 2;
    const int bS = b * Sn;

    const int row8 = tid >> 3;
    const int colx = ((tid & 7) ^ (row8 & 7)) * 16;
    const char* Qg = (const char*)(Qh + (size_t)bS*Kn);

    glds16((const char*)(Kh + (size_t)(bS + stb*64)*Kn) + row8*128 + colx,
           (char*)Kt + w*1024);
    glds16(Qg + row8*128 + colx, (char*)Qt[0] + w*1024);
    __syncthreads();
    const half8 ka0 = ldfrag(Kt, sw*16 + l15, l4);
    const half8 ka1 = ldfrag(Kt, sw*16 + l15, 4 + l4);

    float m[4], z[4];
    #pragma unroll
    for (int r = 0; r < 4; ++r){ m[r] = -3.0e38f; z[r] = 0.f; }

    for (int qc = 0; qc < Sn/64; ++qc){
        const int cur = qc & 1;
        if (qc + 1 < Sn/64)
            glds16(Qg + (size_t)(qc+1)*8192 + row8*128 + colx, (char*)Qt[cur^1] + w*1024);
        f32x4 c[2];
        #pragma unroll
        for (int j = 0; j < 2; ++j){
            const half8 qb0 = ldfrag(Qt[cur], (qh*2+j)*16 + l15, l4);
            const half8 qb1 = ldfrag(Qt[cur], (qh*2+j)*16 + l15, 4 + l4);
            f32x4 cc = {0.f,0.f,0.f,0.f};
            cc = __builtin_amdgcn_mfma_f32_16x16x32_f16(ka0, qb0, cc, 0, 0, 0);
            cc = __builtin_amdgcn_mfma_f32_16x16x32_f16(ka1, qb1, cc, 0, 0, 0);
            c[j] = cc;
        }
        #pragma unroll
        for (int r = 0; r < 4; ++r){
            const float cm = fmaxf(c[0][r], c[1][r]);
            const float mn = fmaxf(m[r], cm);
            z[r] = z[r]*__expf(m[r]-mn) + __expf(c[0][r]-mn) + __expf(c[1][r]-mn);
            m[r] = mn;
        }
        __syncthreads();
    }
    // reduce over the 16 q-columns held across lanes (xor 1,2,4,8)
    #pragma unroll
    for (int d = 1; d < 16; d <<= 1){
        #pragma unroll
        for (int r = 0; r < 4; ++r){
            const float mo = __shfl_xor(m[r], d);
            const float zo = __shfl_xor(z[r], d);
            const float mn = fmaxf(m[r], mo);
            z[r] = z[r]*__expf(m[r]-mn) + zo*__expf(mo-mn);
            m[r] = mn;
        }
    }
    if (l15 == 0){
        const int sl = sw*16 + l4*4;
        #pragma unroll
        for (int r = 0; r < 4; ++r){ mred[qh][sl+r] = m[r]; zred[qh][sl+r] = z[r]; }
    }
    __syncthreads();
    if (tid < 64){
        const float ma = mred[0][tid], mb = mred[1][tid];
        const float mn = fmaxf(ma, mb);
        const float zz = zred[0][tid]*__expf(ma-mn) + zred[1][tid]*__expf(mb-mn);
        Ms[bS + stb*64 + tid] = mn;
        IZ[bS + stb*64 + tid] = 1.0f / zz;
    }
}

// ---- Kernel 4: fused logits -> P -> P@V, 64q x 512d per block, pipelined ----
__global__ __launch_bounds__(512, 2) void attn_kernel(
    const _Float16* __restrict__ Qh, const _Float16* __restrict__ Kh,
    const _Float16* __restrict__ Vt, const float* __restrict__ Ms,
    const float* __restrict__ IZ, float* __restrict__ out)
{
    __shared__ _Float16 Pt[64*64];        // 8 KB
    __shared__ _Float16 Kt[2][64*64];     // 16 KB
    __shared__ _Float16 Vts[2][512*64];   // 128 KB
    const int bid = blockIdx.x;
    const int b = bid & 7, qi = bid >> 3; // b-major -> one b per XCD (L2 locality)
    const int q0 = qi * 64;
    const int tid = threadIdx.x, lane = tid & 63, w = tid >> 6;
    const int l15 = lane & 15, l4 = lane >> 4;
    const int st = w & 3, qtb = (w >> 2) * 2;
    const int bS = b * Sn;

    const int row8 = tid >> 3;
    const int colx = ((tid & 7) ^ (row8 & 7)) * 16;

    // prologue: stage Q through Vts[0], pull B-frags to registers
    glds16((const char*)(Qh + (size_t)(bS + q0)*Kn) + row8*128 + colx,
           (char*)Vts[0] + w*1024);
    __syncthreads();
    half8 qb[2][2];
    #pragma unroll
    for (int j = 0; j < 2; ++j){
        qb[j][0] = ldfrag(Vts[0], (qtb+j)*16 + l15, l4);
        qb[j][1] = ldfrag(Vts[0], (qtb+j)*16 + l15, 4 + l4);
    }
    __syncthreads();

    // staging bases (pre-swizzled global sources)
    const char* Kg = (const char*)(Kh + (size_t)bS*Kn) + row8*128 + colx;       // + sc*8192
    // (row8+64*i)&7 == row8&7, so colx is invariant across the 8 V chunks
    const char* Vg = (const char*)Vt + (size_t)b*Dn*Sn*2 + (size_t)row8*(Sn*2) + colx; // + sc*128 + i*64*Sn*2

    f32x4 acc[4][4];
    #pragma unroll
    for (int i = 0; i < 4; ++i)
        #pragma unroll
        for (int j = 0; j < 4; ++j){ f32x4 zz4 = {0.f,0.f,0.f,0.f}; acc[i][j] = zz4; }

    // stage tile 0
    glds16(Kg, (char*)Kt[0] + w*1024);
    #pragma unroll
    for (int i = 0; i < 8; ++i)
        glds16(Vg + (size_t)i*(64*Sn*2), (char*)Vts[0] + w*1024 + i*8192);

    for (int sc = 0; sc < Sn/64; ++sc){
        const int cur = sc & 1;
        __syncthreads();   // drains stage(sc)

        const float4 mm = *(const float4*)(Ms + bS + sc*64 + st*16 + l4*4);
        const float4 zz = *(const float4*)(IZ + bS + sc*64 + st*16 + l4*4);

        // QK (swapped: A=K rows s, B=Q cols q) + P epilogue (packed 8B writes)
        const half8 a0 = ldfrag(Kt[cur], st*16 + l15, l4);
        const half8 a1 = ldfrag(Kt[cur], st*16 + l15, 4 + l4);
        #pragma unroll
        for (int j = 0; j < 2; ++j){
            f32x4 c = {0.f,0.f,0.f,0.f};
            c = __builtin_amdgcn_mfma_f32_16x16x32_f16(a0, qb[j][0], c, 0, 0, 0);
            c = __builtin_amdgcn_mfma_f32_16x16x32_f16(a1, qb[j][1], c, 0, 0, 0);
            const int q = (qtb+j)*16 + l15;
            half4v p;
            p[0] = (_Float16)(__expf(c[0]-mm.x)*zz.x);
            p[1] = (_Float16)(__expf(c[1]-mm.y)*zz.y);
            p[2] = (_Float16)(__expf(c[2]-mm.z)*zz.z);
            p[3] = (_Float16)(__expf(c[3]-mm.w)*zz.w);
            const int sb2 = (st*16 + l4*4)*2;
            *(half4v*)((char*)Pt + q*128 + (sb2 ^ ((q & 7) << 4))) = p;
        }
        __syncthreads();   // P visible; buf^1 free

        if (sc + 1 < Sn/64){   // prefetch next tile; hides under PV
            glds16(Kg + (size_t)(sc+1)*8192, (char*)Kt[cur^1] + w*1024);
            #pragma unroll
            for (int i = 0; i < 8; ++i)
                glds16(Vg + (size_t)(sc+1)*128 + (size_t)i*(64*Sn*2),
                       (char*)Vts[cur^1] + w*1024 + i*8192);
        }

        // PV: wave owns d slice [w*64, w*64+64)
        #pragma unroll
        for (int ks = 0; ks < 2; ++ks){
            half8 pa[4];
            #pragma unroll
            for (int qt = 0; qt < 4; ++qt)
                pa[qt] = ldfrag(Pt, qt*16 + l15, ks*4 + l4);
            #pragma unroll
            for (int dt = 0; dt < 4; ++dt){
                const half8 vb = ldfrag(Vts[cur], w*64 + dt*16 + l15, ks*4 + l4);
                #pragma unroll
                for (int qt = 0; qt < 4; ++qt)
                    acc[qt][dt] = __builtin_amdgcn_mfma_f32_16x16x32_f16(pa[qt], vb, acc[qt][dt], 0, 0, 0);
            }
        }
    }

    float* ob = out + (size_t)(bS + q0)*Dn;
    #pragma unroll
    for (int qt = 0; qt < 4; ++qt){
        const int q = qt*16 + l4*4;
        #pragma unroll
        for (int dt = 0; dt < 4; ++dt){
            const int d = w*64 + dt*16 + l15;
            #pragma unroll
            for (int r = 0; r < 4; ++r)
                ob[(size_t)(q+r)*Dn + d] = acc[qt][dt][r];
        }
    }
}

extern "C" void kernel_launch(void* const* d_in, const int* in_sizes, int n_in,
                              void* d_out, int out_size, void* d_ws, size_t ws_size,
                              hipStream_t stream)
{
    const float* X  = (const float*)d_in[0];
    const float* Wk = (const float*)d_in[1];
    const float* bk = (const float*)d_in[2];
    const float* Wq = (const float*)d_in[3];
    const float* bq = (const float*)d_in[4];
    float* out = (float*)d_out;

    char* ws = (char*)d_ws;
    _Float16* Qh   = (_Float16*)ws;                                  // 2 MB
    _Float16* Kh   = (_Float16*)(ws + ((size_t)2 << 20));            // 2 MB
    _Float16* Vt   = (_Float16*)(ws + ((size_t)4 << 20));            // 16 MB
    float*    Ms   = (float*)(ws + ((size_t)20 << 20));              // 64 KB
    float*    IZ   = (float*)(ws + ((size_t)20 << 20) + (1 << 16));  // 64 KB
    _Float16* Wt16 = (_Float16*)(ws + ((size_t)20 << 20) + (2 << 16)); // 128 KB

    wtrans_kernel<<<dim3(128), dim3(256), 0, stream>>>(Wk, Wq, Wt16);
    qkproj_kernel<<<dim3((Bn*Sn)/64), dim3(256), 0, stream>>>(X, Wt16, bk, bq, Qh, Kh);
    transpose_kernel<<<dim3(Bn*(Sn/64)*(Dn/64)), dim3(256), 0, stream>>>(X, Vt);
    stats_kernel<<<dim3(Bn*(Sn/64)), dim3(512), 0, stream>>>(Qh, Kh, Ms, IZ);
    attn_kernel<<<dim3(Bn*(Sn/64)), dim3(512), 0, stream>>>(Qh, Kh, Vt, Ms, IZ, out);
}

// Round 4
// 92.031 us; speedup vs baseline: 1.5943x; 1.2410x over previous
//
#include <hip/hip_runtime.h>
#include <hip/hip_bf16.h>

#define Bn 8
#define Sn 2048
#define Dn 512
#define Kn 64

typedef _Float16 half8 __attribute__((ext_vector_type(8)));
typedef _Float16 half4v __attribute__((ext_vector_type(4)));
typedef float f32x4 __attribute__((ext_vector_type(4)));

#define MFMA16(a,b,c) __builtin_amdgcn_mfma_f32_16x16x32_f16(a,b,c,0,0,0)

// async global->LDS, 16B per lane (qkproj staging only)
__device__ __forceinline__ void glds16(const void* g, void* l){
    __builtin_amdgcn_global_load_lds(
        (const __attribute__((address_space(1))) unsigned int*)g,
        (__attribute__((address_space(3))) unsigned int*)l, 16, 0, 0);
}

// LDS tiles [rows][64] f16 (128B rows), XOR-swizzled on 16B granules.
__device__ __forceinline__ half8 ldfrag(const _Float16* base, int row, int k8){
    const int scol = k8 ^ (row & 7);
    return *(const half8*)((const char*)base + row*128 + scol*16);
}

// Fragment layouts in global memory (16B granules, lane = l4*16+l15):
//  Qh2/Kh2: granule (t*2+ks)*64+lane = M[t*16+l15][ks*32+l4*8 .. +8]   (t = global 16-row tile)
//  Vt2:     granule (((b*32+sc)*2+ks)*32+dt)*64+lane = V[dt*16+l15][sc*64+(ks*4+l4)*8 .. +8]

// ---- Kernel 0: W transpose+cast: Wt16[n][k], n<64 -> Wq col n, else Wk ----
__global__ __launch_bounds__(256) void wtrans_kernel(
    const float* __restrict__ Wk, const float* __restrict__ Wq,
    _Float16* __restrict__ Wt16)
{
    const int n = blockIdx.x;          // 0..127
    const int t = threadIdx.x;
    const float* src = (n < 64) ? Wq : Wk;
    const int nn = n & 63;
    #pragma unroll
    for (int i = 0; i < 2; ++i){
        const int k = t + 256*i;
        Wt16[(size_t)n*Dn + k] = (_Float16)src[(size_t)k*Kn + nn];
    }
}

// ---- Kernel 1: Q/K projection GEMM -> fragmented Qh2/Kh2 ----
__global__ __launch_bounds__(256) void qkproj_kernel(
    const float* __restrict__ X, const _Float16* __restrict__ Wt16,
    const float* __restrict__ bk, const float* __restrict__ bq,
    _Float16* __restrict__ Qh2, _Float16* __restrict__ Kh2)
{
    __shared__ _Float16 Xt[64*64];
    __shared__ _Float16 Wt[128*64];
    const int q0  = blockIdx.x * 64;
    const int tid = threadIdx.x, lane = tid & 63, w = tid >> 6;

    f32x4 acc[4][2];
    #pragma unroll
    for (int i = 0; i < 4; ++i)
        #pragma unroll
        for (int j = 0; j < 2; ++j){ f32x4 z = {0.f,0.f,0.f,0.f}; acc[i][j] = z; }

    for (int kc = 0; kc < Dn/64; ++kc){
        __syncthreads();
        #pragma unroll
        for (int i = 0; i < 4; ++i){
            const int c  = tid + 256*i;
            const int rw = c >> 3, cw = c & 7;
            glds16((const char*)Wt16 + (size_t)rw*1024 + kc*128 + ((cw ^ (rw & 7))*16),
                   (char*)Wt + w*1024 + i*4096);
        }
        #pragma unroll
        for (int i = 0; i < 2; ++i){
            const int g = tid + 256*i;
            const int row = g >> 3, col = g & 7;
            const float* s = X + (size_t)(q0 + row)*Dn + kc*64 + col*8;
            const float4 v0 = *(const float4*)s;
            const float4 v1 = *(const float4*)(s + 4);
            half8 h;
            h[0]=(_Float16)v0.x; h[1]=(_Float16)v0.y; h[2]=(_Float16)v0.z; h[3]=(_Float16)v0.w;
            h[4]=(_Float16)v1.x; h[5]=(_Float16)v1.y; h[6]=(_Float16)v1.z; h[7]=(_Float16)v1.w;
            *(half8*)((char*)Xt + row*128 + ((col ^ (row & 7))*16)) = h;
        }
        __syncthreads();
        #pragma unroll
        for (int ks = 0; ks < 2; ++ks){
            half8 a[4];
            #pragma unroll
            for (int qt = 0; qt < 4; ++qt)
                a[qt] = ldfrag(Xt, qt*16 + (lane & 15), ks*4 + (lane >> 4));
            #pragma unroll
            for (int nt = 0; nt < 2; ++nt){
                const half8 bfr = ldfrag(Wt, w*32 + nt*16 + (lane & 15), ks*4 + (lane >> 4));
                #pragma unroll
                for (int qt = 0; qt < 4; ++qt)
                    acc[qt][nt] = MFMA16(a[qt], bfr, acc[qt][nt]);
            }
        }
    }
    // epilogue: bias + pack into [64][128] f16 tile, then fragment stores
    __syncthreads();
    _Float16* tile16 = Wt;   // reuse as [64 q][128 n]
    #pragma unroll
    for (int qt = 0; qt < 4; ++qt){
        const int ql = qt*16 + (lane >> 4)*4;
        #pragma unroll
        for (int nt = 0; nt < 2; ++nt){
            const int n = w*32 + nt*16 + (lane & 15);
            const float bias = (n < 64) ? bq[n] : bk[n - 64];
            #pragma unroll
            for (int r = 0; r < 4; ++r)
                tile16[(ql + r)*128 + n] = (_Float16)(acc[qt][nt][r] + bias);
        }
    }
    __syncthreads();
    #pragma unroll
    for (int i = 0; i < 4; ++i){
        const int g   = tid + 256*i;        // 0..1023
        const int isK = g >> 9, gg = g & 511;
        const int ks  = gg >> 8, qtl = (gg >> 6) & 3, ln = gg & 63;
        const int l4g = ln >> 4, l15g = ln & 15;
        const half8 h = *(const half8*)&tile16[(qtl*16 + l15g)*128 + isK*64 + ks*32 + l4g*8];
        const size_t qtg = (size_t)blockIdx.x*4 + qtl;
        _Float16* dst = (isK ? Kh2 : Qh2) + ((qtg*2 + ks)*64 + ln)*8;
        *(half8*)dst = h;
    }
}

// ---- Kernel 2: V transpose + cast -> fragmented Vt2 ----
__global__ __launch_bounds__(256) void transpose_kernel(
    const float* __restrict__ X, _Float16* __restrict__ Vt2)
{
    __shared__ _Float16 tile[64*72];   // [d 64][s 64] pad->72 (16B-aligned rows)
    const int bid = blockIdx.x;
    const int b  = bid >> 8;
    const int sb = (bid >> 3) & 31;
    const int dq = bid & 7;
    const int tid = threadIdx.x;
    #pragma unroll
    for (int i = 0; i < 4; ++i){
        const int sl = (tid >> 4) + i*16;
        const int dl = (tid & 15) * 4;
        const float4 v = *(const float4*)(X + ((size_t)(b*Sn + sb*64 + sl))*Dn + dq*64 + dl);
        tile[(dl+0)*72 + sl] = (_Float16)v.x;
        tile[(dl+1)*72 + sl] = (_Float16)v.y;
        tile[(dl+2)*72 + sl] = (_Float16)v.z;
        tile[(dl+3)*72 + sl] = (_Float16)v.w;
    }
    __syncthreads();
    #pragma unroll
    for (int i = 0; i < 2; ++i){
        const int g   = tid + 256*i;        // 0..511
        const int ks  = g >> 8, dtl = (g >> 6) & 3, ln = g & 63;
        const int l4g = ln >> 4, l15g = ln & 15;
        const half8 h = *(const half8*)&tile[(dtl*16 + l15g)*72 + (ks*4 + l4g)*8];
        const size_t gran = (((size_t)(b*32 + sb)*2 + ks)*32 + dq*4 + dtl)*64 + ln;
        *(half8*)(Vt2 + gran*8) = h;
    }
}

// ---- Kernel 3: per-(b,s) column stats over q; direct fragment loads, no LDS staging ----
#define STATS_BODY(qc_, QB0C,QB1C,QB2C,QB3C, QB0N,QB1N,QB2N,QB3N) do { \
    const int qn_ = ((qc_) < 31) ? (qc_) + 1 : 31; \
    QB0N = *(const half8*)(Qh2 + ((size_t)((qgb + qn_*4 + qh2 + 0)*2 + 0)*64 + lane)*8); \
    QB1N = *(const half8*)(Qh2 + ((size_t)((qgb + qn_*4 + qh2 + 0)*2 + 1)*64 + lane)*8); \
    QB2N = *(const half8*)(Qh2 + ((size_t)((qgb + qn_*4 + qh2 + 1)*2 + 0)*64 + lane)*8); \
    QB3N = *(const half8*)(Qh2 + ((size_t)((qgb + qn_*4 + qh2 + 1)*2 + 1)*64 + lane)*8); \
    f32x4 c0 = {0.f,0.f,0.f,0.f}, c1 = {0.f,0.f,0.f,0.f}; \
    c0 = MFMA16(ka0, QB0C, c0); c0 = MFMA16(ka1, QB1C, c0); \
    c1 = MFMA16(ka0, QB2C, c1); c1 = MFMA16(ka1, QB3C, c1); \
    _Pragma("unroll") \
    for (int r = 0; r < 4; ++r){ \
        const float cm = fmaxf(c0[r], c1[r]); \
        const float mn = fmaxf(m[r], cm); \
        z[r] = z[r]*__expf(m[r]-mn) + __expf(c0[r]-mn) + __expf(c1[r]-mn); \
        m[r] = mn; \
    } \
} while(0)

__global__ __launch_bounds__(512, 2) void stats_kernel(
    const _Float16* __restrict__ Qh2, const _Float16* __restrict__ Kh2,
    float* __restrict__ Ms, float* __restrict__ IZ)
{
    __shared__ float mred[2][64];
    __shared__ float zred[2][64];
    const int bid = blockIdx.x;
    const int b = bid & 7, stb = bid >> 3;
    const int tid = threadIdx.x, lane = tid & 63, w = tid >> 6;
    const int l15 = lane & 15, l4 = lane >> 4;
    const int sw = w & 3, qh = w >> 2, qh2 = qh*2;
    const int qgb = b*128;

    const half8 ka0 = *(const half8*)(Kh2 + ((size_t)((b*128 + stb*4 + sw)*2 + 0)*64 + lane)*8);
    const half8 ka1 = *(const half8*)(Kh2 + ((size_t)((b*128 + stb*4 + sw)*2 + 1)*64 + lane)*8);

    float m[4], z[4];
    #pragma unroll
    for (int r = 0; r < 4; ++r){ m[r] = -3.0e38f; z[r] = 0.f; }

    half8 qbA0, qbA1, qbA2, qbA3, qbB0, qbB1, qbB2, qbB3;
    qbA0 = *(const half8*)(Qh2 + ((size_t)((qgb + qh2 + 0)*2 + 0)*64 + lane)*8);
    qbA1 = *(const half8*)(Qh2 + ((size_t)((qgb + qh2 + 0)*2 + 1)*64 + lane)*8);
    qbA2 = *(const half8*)(Qh2 + ((size_t)((qgb + qh2 + 1)*2 + 0)*64 + lane)*8);
    qbA3 = *(const half8*)(Qh2 + ((size_t)((qgb + qh2 + 1)*2 + 1)*64 + lane)*8);

    for (int qc = 0; qc < 32; qc += 2){
        STATS_BODY(qc,   qbA0,qbA1,qbA2,qbA3, qbB0,qbB1,qbB2,qbB3);
        STATS_BODY(qc+1, qbB0,qbB1,qbB2,qbB3, qbA0,qbA1,qbA2,qbA3);
    }
    // reduce over the 16 q-columns held across lanes
    #pragma unroll
    for (int d = 1; d < 16; d <<= 1){
        #pragma unroll
        for (int r = 0; r < 4; ++r){
            const float mo = __shfl_xor(m[r], d);
            const float zo = __shfl_xor(z[r], d);
            const float mn = fmaxf(m[r], mo);
            z[r] = z[r]*__expf(m[r]-mn) + zo*__expf(mo-mn);
            m[r] = mn;
        }
    }
    if (l15 == 0){
        const int sl = sw*16 + l4*4;
        #pragma unroll
        for (int r = 0; r < 4; ++r){ mred[qh][sl+r] = m[r]; zred[qh][sl+r] = z[r]; }
    }
    __syncthreads();
    if (tid < 64){
        const float ma = mred[0][tid], mb = mred[1][tid];
        const float mn = fmaxf(ma, mb);
        const float zz = zred[0][tid]*__expf(ma-mn) + zred[1][tid]*__expf(mb-mn);
        Ms[b*Sn + stb*64 + tid] = mn;
        IZ[b*Sn + stb*64 + tid] = 1.0f / zz;
    }
}

// ---- Kernel 4: fused logits -> P -> P@V; direct L2->reg fragments, P via dbuf LDS ----
#define ATTN_BODY(sc_, KA, KAN, MM, ZZ, MMN, ZZN, VB, VBN, PT) do { \
    const int scn_ = ((sc_) < 31) ? (sc_) + 1 : 31; \
    f32x4 c0 = {0.f,0.f,0.f,0.f}, c1 = {0.f,0.f,0.f,0.f}; \
    c0 = MFMA16(KA[0], qb00, c0); c0 = MFMA16(KA[1], qb01, c0); \
    c1 = MFMA16(KA[0], qb10, c1); c1 = MFMA16(KA[1], qb11, c1); \
    KAN[0] = *(const half8*)(Kh2 + ((size_t)((kb + scn_*4 + st)*2 + 0)*64 + lane)*8); \
    KAN[1] = *(const half8*)(Kh2 + ((size_t)((kb + scn_*4 + st)*2 + 1)*64 + lane)*8); \
    MMN = *(const float4*)(Msb + scn_*64 + soff); \
    ZZN = *(const float4*)(IZb + scn_*64 + soff); \
    half4v p0, p1; \
    p0[0] = (_Float16)(__expf(c0[0]-MM.x)*ZZ.x); \
    p0[1] = (_Float16)(__expf(c0[1]-MM.y)*ZZ.y); \
    p0[2] = (_Float16)(__expf(c0[2]-MM.z)*ZZ.z); \
    p0[3] = (_Float16)(__expf(c0[3]-MM.w)*ZZ.w); \
    p1[0] = (_Float16)(__expf(c1[0]-MM.x)*ZZ.x); \
    p1[1] = (_Float16)(__expf(c1[1]-MM.y)*ZZ.y); \
    p1[2] = (_Float16)(__expf(c1[2]-MM.z)*ZZ.z); \
    p1[3] = (_Float16)(__expf(c1[3]-MM.w)*ZZ.w); \
    { const int q_  = qtb16 + l15; \
      *(half4v*)((char*)(PT) + q_*128 + (sb2 ^ ((q_ & 7) << 4))) = p0; \
      const int q2_ = q_ + 16; \
      *(half4v*)((char*)(PT) + q2_*128 + (sb2 ^ ((q2_ & 7) << 4))) = p1; } \
    asm volatile("s_waitcnt lgkmcnt(0)\n\ts_barrier" ::: "memory"); \
    _Pragma("unroll") \
    for (int ks = 0; ks < 2; ++ks) \
        _Pragma("unroll") \
        for (int dtl = 0; dtl < 4; ++dtl) \
            VBN[ks*4+dtl] = *(const half8*)(Vt2 + ((size_t)(((bV + scn_)*2 + ks)*32 + w4 + dtl)*64 + lane)*8); \
    _Pragma("unroll") \
    for (int ks = 0; ks < 2; ++ks){ \
        const half8 pa0 = ldfrag(PT, 0*16 + l15, ks*4 + l4); \
        const half8 pa1 = ldfrag(PT, 1*16 + l15, ks*4 + l4); \
        const half8 pa2 = ldfrag(PT, 2*16 + l15, ks*4 + l4); \
        const half8 pa3 = ldfrag(PT, 3*16 + l15, ks*4 + l4); \
        _Pragma("unroll") \
        for (int dtl = 0; dtl < 4; ++dtl){ \
            acc[0][dtl] = MFMA16(pa0, VB[ks*4+dtl], acc[0][dtl]); \
            acc[1][dtl] = MFMA16(pa1, VB[ks*4+dtl], acc[1][dtl]); \
            acc[2][dtl] = MFMA16(pa2, VB[ks*4+dtl], acc[2][dtl]); \
            acc[3][dtl] = MFMA16(pa3, VB[ks*4+dtl], acc[3][dtl]); \
        } \
    } \
} while(0)

__global__ __launch_bounds__(512, 2) void attn_kernel(
    const _Float16* __restrict__ Qh2, const _Float16* __restrict__ Kh2,
    const _Float16* __restrict__ Vt2, const float* __restrict__ Ms,
    const float* __restrict__ IZ, float* __restrict__ out)
{
    __shared__ _Float16 Pt[2][64*64];   // 16 KB total
    const int bid = blockIdx.x;
    const int b = bid & 7, qi = bid >> 3;   // b-major: one batch per XCD
    const int q0 = qi * 64;
    const int tid = threadIdx.x, lane = tid & 63, w = tid >> 6;
    const int l15 = lane & 15, l4 = lane >> 4;
    const int st = w & 3, qtb = (w >> 2) * 2, qtb16 = qtb*16;
    const int w4 = w * 4;
    const int kb = b * 128;
    const int bV = b * 32;
    const int sb2 = (st*16 + l4*4) * 2;
    const int soff = st*16 + l4*4;
    const float* Msb = Ms + b * Sn;
    const float* IZb = IZ + b * Sn;

    // Q fragments (once)
    const int qgb = kb + (q0 >> 4);
    half8 qb00, qb01, qb10, qb11;
    qb00 = *(const half8*)(Qh2 + ((size_t)((qgb + qtb + 0)*2 + 0)*64 + lane)*8);
    qb01 = *(const half8*)(Qh2 + ((size_t)((qgb + qtb + 0)*2 + 1)*64 + lane)*8);
    qb10 = *(const half8*)(Qh2 + ((size_t)((qgb + qtb + 1)*2 + 0)*64 + lane)*8);
    qb11 = *(const half8*)(Qh2 + ((size_t)((qgb + qtb + 1)*2 + 1)*64 + lane)*8);

    // prefetch sc=0
    half8 kaA[2], kaB[2];
    half8 vbA[8], vbB[8];
    float4 mmA, zzA, mmB, zzB;
    kaA[0] = *(const half8*)(Kh2 + ((size_t)((kb + st)*2 + 0)*64 + lane)*8);
    kaA[1] = *(const half8*)(Kh2 + ((size_t)((kb + st)*2 + 1)*64 + lane)*8);
    mmA = *(const float4*)(Msb + soff);
    zzA = *(const float4*)(IZb + soff);
    #pragma unroll
    for (int ks = 0; ks < 2; ++ks)
        #pragma unroll
        for (int dtl = 0; dtl < 4; ++dtl)
            vbA[ks*4+dtl] = *(const half8*)(Vt2 + ((size_t)((bV*2 + ks)*32 + w4 + dtl)*64 + lane)*8);

    f32x4 acc[4][4];
    #pragma unroll
    for (int i = 0; i < 4; ++i)
        #pragma unroll
        for (int j = 0; j < 4; ++j){ f32x4 zz4 = {0.f,0.f,0.f,0.f}; acc[i][j] = zz4; }

    for (int sc = 0; sc < 32; sc += 2){
        ATTN_BODY(sc,   kaA, kaB, mmA, zzA, mmB, zzB, vbA, vbB, Pt[0]);
        ATTN_BODY(sc+1, kaB, kaA, mmB, zzB, mmA, zzA, vbB, vbA, Pt[1]);
    }

    float* ob = out + (size_t)(b*Sn + q0)*Dn;
    #pragma unroll
    for (int qt = 0; qt < 4; ++qt){
        const int q = qt*16 + l4*4;
        #pragma unroll
        for (int dtl = 0; dtl < 4; ++dtl){
            const int d = w4*16 + dtl*16 + l15;
            #pragma unroll
            for (int r = 0; r < 4; ++r)
                ob[(size_t)(q + r)*Dn + d] = acc[qt][dtl][r];
        }
    }
}

extern "C" void kernel_launch(void* const* d_in, const int* in_sizes, int n_in,
                              void* d_out, int out_size, void* d_ws, size_t ws_size,
                              hipStream_t stream)
{
    const float* X  = (const float*)d_in[0];
    const float* Wk = (const float*)d_in[1];
    const float* bk = (const float*)d_in[2];
    const float* Wq = (const float*)d_in[3];
    const float* bq = (const float*)d_in[4];
    float* out = (float*)d_out;

    char* ws = (char*)d_ws;
    _Float16* Qh2  = (_Float16*)ws;                                  // 2 MB
    _Float16* Kh2  = (_Float16*)(ws + ((size_t)2 << 20));            // 2 MB
    _Float16* Vt2  = (_Float16*)(ws + ((size_t)4 << 20));            // 16 MB
    float*    Ms   = (float*)(ws + ((size_t)20 << 20));              // 64 KB
    float*    IZ   = (float*)(ws + ((size_t)20 << 20) + (1 << 16));  // 64 KB
    _Float16* Wt16 = (_Float16*)(ws + ((size_t)20 << 20) + (2 << 16)); // 128 KB

    wtrans_kernel<<<dim3(128), dim3(256), 0, stream>>>(Wk, Wq, Wt16);
    qkproj_kernel<<<dim3((Bn*Sn)/64), dim3(256), 0, stream>>>(X, Wt16, bk, bq, Qh2, Kh2);
    transpose_kernel<<<dim3(Bn*(Sn/64)*(Dn/64)), dim3(256), 0, stream>>>(X, Vt2);
    stats_kernel<<<dim3(Bn*(Sn/64)), dim3(512), 0, stream>>>(Qh2, Kh2, Ms, IZ);
    attn_kernel<<<dim3(Bn*(Sn/64)), dim3(512), 0, stream>>>(Qh2, Kh2, Vt2, Ms, IZ, out);
}

// Round 5
// 86.930 us; speedup vs baseline: 1.6878x; 1.0587x over previous
//
#include <hip/hip_runtime.h>
#include <hip/hip_bf16.h>

#define Bn 8
#define Sn 2048
#define Dn 512
#define Kn 64

typedef _Float16 half8 __attribute__((ext_vector_type(8)));
typedef _Float16 half4v __attribute__((ext_vector_type(4)));
typedef float f32x4 __attribute__((ext_vector_type(4)));

#define MFMA16(a,b,c) __builtin_amdgcn_mfma_f32_16x16x32_f16(a,b,c,0,0,0)

// LDS tiles [rows][64] f16 (128B rows), XOR-swizzled on 16B granules.
__device__ __forceinline__ half8 ldfrag(const _Float16* base, int row, int k8){
    const int scol = k8 ^ (row & 7);
    return *(const half8*)((const char*)base + row*128 + scol*16);
}

// Fragment layouts in global memory (16B granules, lane = l4*16+l15):
//  Qh2/Kh2: granule (t*2+ks)*64+lane = M[t*16+l15][ks*32+l4*8 .. +8]   (t = global 16-row tile)
//  Vt2:     granule (((b*32+sc)*2+ks)*32+dt)*64+lane = V[dt*16+l15][sc*64+(ks*4+l4)*8 .. +8]

// ---- Kernel 0: W transpose+cast: Wt16[n][k], n<64 -> Wq col n, else Wk ----
__global__ __launch_bounds__(256) void wtrans_kernel(
    const float* __restrict__ Wk, const float* __restrict__ Wq,
    _Float16* __restrict__ Wt16)
{
    const int n = blockIdx.x;          // 0..127
    const int t = threadIdx.x;
    const float* src = (n < 64) ? Wq : Wk;
    const int nn = n & 63;
    #pragma unroll
    for (int i = 0; i < 2; ++i){
        const int k = t + 256*i;
        Wt16[(size_t)n*Dn + k] = (_Float16)src[(size_t)k*Kn + nn];
    }
}

// ---- Kernel 1: fused Q/K projection + V transpose (32 rows per block) ----
// Xt swizzle: granule phys = g ^ (row&7) ^ (row>>3)  (3-bit XOR)
__global__ __launch_bounds__(256, 2) void prep_kernel(
    const float* __restrict__ X, const _Float16* __restrict__ Wt16,
    const float* __restrict__ bk, const float* __restrict__ bq,
    _Float16* __restrict__ Qh2, _Float16* __restrict__ Kh2,
    _Float16* __restrict__ Vt2)
{
    __shared__ _Float16 Xt[2][32*64];   // 8 KB
    const int bid = blockIdx.x;
    const int b = bid & 7, sb32 = bid >> 3;     // b-major -> XCD locality
    const int tid = threadIdx.x, lane = tid & 63, w = tid >> 6;
    const int l15 = lane & 15, l4 = lane >> 4;

    // stage mapping: one half8 granule per thread per kc
    const int srow = tid >> 3, sg = tid & 7;
    const float* Xs = X + ((size_t)(b*Sn + sb32*32) + srow)*Dn + sg*8;
    const int sdst = srow*128 + (((sg ^ (srow & 7) ^ (srow >> 3)) & 7) * 16);

    // W fragment pointers (B-operand frags are contiguous 16B in Wt16)
    const int n0 = w*32 + l15;
    const _Float16* Wp0 = Wt16 + (size_t)n0*Dn + l4*8;
    const _Float16* Wp1 = Wp0 + (size_t)16*Dn;

    f32x4 acc[2][2];
    #pragma unroll
    for (int i = 0; i < 2; ++i)
        #pragma unroll
        for (int j = 0; j < 2; ++j){ f32x4 z = {0.f,0.f,0.f,0.f}; acc[i][j] = z; }

    // prologue: stage kc=0
    {
        const float4 v0 = *(const float4*)(Xs);
        const float4 v1 = *(const float4*)(Xs + 4);
        half8 h;
        h[0]=(_Float16)v0.x; h[1]=(_Float16)v0.y; h[2]=(_Float16)v0.z; h[3]=(_Float16)v0.w;
        h[4]=(_Float16)v1.x; h[5]=(_Float16)v1.y; h[6]=(_Float16)v1.z; h[7]=(_Float16)v1.w;
        *(half8*)((char*)Xt[0] + sdst) = h;
    }
    __syncthreads();

    const int dcol = w*16 + l15;     // V-emit column (d within kc chunk)
    #pragma unroll
    for (int kc = 0; kc < 8; ++kc){
        const _Float16* XtC = Xt[kc & 1];
        float4 nv0, nv1;
        if (kc < 7){
            nv0 = *(const float4*)(Xs + (kc+1)*64);
            nv1 = *(const float4*)(Xs + (kc+1)*64 + 4);
        }
        const half8 wf00 = *(const half8*)(Wp0 + kc*64);
        const half8 wf01 = *(const half8*)(Wp0 + kc*64 + 32);
        const half8 wf10 = *(const half8*)(Wp1 + kc*64);
        const half8 wf11 = *(const half8*)(Wp1 + kc*64 + 32);
        #pragma unroll
        for (int ks = 0; ks < 2; ++ks){
            #pragma unroll
            for (int qt = 0; qt < 2; ++qt){
                const int rw = qt*16 + l15;
                const int g = ((ks*4 + l4) ^ (rw & 7) ^ (rw >> 3)) & 7;
                const half8 a = *(const half8*)((const char*)XtC + rw*128 + g*16);
                acc[qt][0] = MFMA16(a, ks ? wf01 : wf00, acc[qt][0]);
                acc[qt][1] = MFMA16(a, ks ? wf11 : wf10, acc[qt][1]);
            }
        }
        // V-emit: one Vt2 granule per thread (conflict-free column gather)
        {
            half8 hv;
            #pragma unroll
            for (int e = 0; e < 8; ++e){
                const int rw = l4*8 + e;
                const int g = ((dcol >> 3) ^ e ^ l4) & 7;
                hv[e] = XtC[rw*64 + g*8 + (dcol & 7)];
            }
            const size_t G = (((size_t)(b*32 + (sb32 >> 1))*2 + (sb32 & 1))*32 + kc*4 + w)*64 + lane;
            *(half8*)(Vt2 + G*8) = hv;
        }
        if (kc < 7){
            half8 h;
            h[0]=(_Float16)nv0.x; h[1]=(_Float16)nv0.y; h[2]=(_Float16)nv0.z; h[3]=(_Float16)nv0.w;
            h[4]=(_Float16)nv1.x; h[5]=(_Float16)nv1.y; h[6]=(_Float16)nv1.z; h[7]=(_Float16)nv1.w;
            *(half8*)((char*)Xt[(kc+1) & 1] + sdst) = h;
        }
        __syncthreads();
    }

    // epilogue: bias + pack [32 q][128 n] + fragment stores
    _Float16* tile16 = &Xt[0][0];   // 8 KB, stride 128
    #pragma unroll
    for (int qt = 0; qt < 2; ++qt){
        const int ql = qt*16 + l4*4;
        #pragma unroll
        for (int nt = 0; nt < 2; ++nt){
            const int n = w*32 + nt*16 + l15;
            const float bias = (n < 64) ? bq[n] : bk[n - 64];
            #pragma unroll
            for (int r = 0; r < 4; ++r)
                tile16[(ql + r)*128 + n] = (_Float16)(acc[qt][nt][r] + bias);
        }
    }
    __syncthreads();
    #pragma unroll
    for (int i = 0; i < 2; ++i){
        const int g = tid + 256*i;          // 0..511
        const int isK = g >> 8, qtl = (g >> 7) & 1, ks = (g >> 6) & 1, ln = g & 63;
        const int l4g = ln >> 4, l15g = ln & 15;
        const half8 h = *(const half8*)&tile16[(qtl*16 + l15g)*128 + isK*64 + ks*32 + l4g*8];
        const size_t tg = (size_t)b*128 + sb32*2 + qtl;
        _Float16* dst = (isK ? Kh2 : Qh2) + ((tg*2 + ks)*64 + ln)*8;
        *(half8*)dst = h;
    }
}

// ---- Kernel 2: per-(b,s) column stats over q; pointer-bumped fragment loads ----
#define SBODY(QC0,QC1,QC2,QC3, QN0,QN1,QN2,QN3) do { \
    QN0 = *(const half8*)(Qp); \
    QN1 = *(const half8*)(Qp + 1024); \
    QN2 = *(const half8*)(Qp + 2048); \
    QN3 = *(const half8*)(Qp + 3072); \
    Qp += 8192; \
    f32x4 c0 = {0.f,0.f,0.f,0.f}, c1 = {0.f,0.f,0.f,0.f}; \
    c0 = MFMA16(ka0, QC0, c0); c0 = MFMA16(ka1, QC1, c0); \
    c1 = MFMA16(ka0, QC2, c1); c1 = MFMA16(ka1, QC3, c1); \
    _Pragma("unroll") \
    for (int r = 0; r < 4; ++r){ \
        const float cm = fmaxf(c0[r], c1[r]); \
        const float mn = fmaxf(m[r], cm); \
        z[r] = z[r]*__expf(m[r]-mn) + __expf(c0[r]-mn) + __expf(c1[r]-mn); \
        m[r] = mn; \
    } \
} while(0)

__global__ __launch_bounds__(512, 2) void stats_kernel(
    const _Float16* __restrict__ Qh2, const _Float16* __restrict__ Kh2,
    float* __restrict__ Ms, float* __restrict__ IZ)
{
    __shared__ float mred[2][64];
    __shared__ float zred[2][64];
    const int bid = blockIdx.x;
    const int b = bid & 7, stb = bid >> 3;
    const int tid = threadIdx.x, lane = tid & 63, w = tid >> 6;
    const int l15 = lane & 15, l4 = lane >> 4;
    const int sw = w & 3, qh = w >> 2, qh2 = qh*2;

    const half8 ka0 = *(const half8*)(Kh2 + ((size_t)((b*128 + stb*4 + sw)*2 + 0)*64 + lane)*8);
    const half8 ka1 = *(const half8*)(Kh2 + ((size_t)((b*128 + stb*4 + sw)*2 + 1)*64 + lane)*8);

    const char* Qp = (const char*)Qh2 + (size_t)(b*128 + qh2)*2048 + lane*16;

    float m[4], z[4];
    #pragma unroll
    for (int r = 0; r < 4; ++r){ m[r] = -3.0e38f; z[r] = 0.f; }

    half8 qbA0, qbA1, qbA2, qbA3, qbB0, qbB1, qbB2, qbB3;
    qbA0 = *(const half8*)(Qp);
    qbA1 = *(const half8*)(Qp + 1024);
    qbA2 = *(const half8*)(Qp + 2048);
    qbA3 = *(const half8*)(Qp + 3072);
    Qp += 8192;

    for (int qc = 0; qc < 32; qc += 2){
        SBODY(qbA0,qbA1,qbA2,qbA3, qbB0,qbB1,qbB2,qbB3);
        SBODY(qbB0,qbB1,qbB2,qbB3, qbA0,qbA1,qbA2,qbA3);
    }
    #pragma unroll
    for (int d = 1; d < 16; d <<= 1){
        #pragma unroll
        for (int r = 0; r < 4; ++r){
            const float mo = __shfl_xor(m[r], d);
            const float zo = __shfl_xor(z[r], d);
            const float mn = fmaxf(m[r], mo);
            z[r] = z[r]*__expf(m[r]-mn) + zo*__expf(mo-mn);
            m[r] = mn;
        }
    }
    if (l15 == 0){
        const int sl = sw*16 + l4*4;
        #pragma unroll
        for (int r = 0; r < 4; ++r){ mred[qh][sl+r] = m[r]; zred[qh][sl+r] = z[r]; }
    }
    __syncthreads();
    if (tid < 64){
        const float ma = mred[0][tid], mb = mred[1][tid];
        const float mn = fmaxf(ma, mb);
        const float zz = zred[0][tid]*__expf(ma-mn) + zred[1][tid]*__expf(mb-mn);
        Ms[b*Sn + stb*64 + tid] = mn;
        IZ[b*Sn + stb*64 + tid] = 1.0f / zz;
    }
}

// ---- Kernel 3: fused logits -> P -> P@V; 4-wave 64q x 256d blocks ----
#define WRP(PT, QT, C, MM, ZZ) do { \
    half4v p; \
    p[0] = (_Float16)(__expf(C[0]-MM.x)*ZZ.x); \
    p[1] = (_Float16)(__expf(C[1]-MM.y)*ZZ.y); \
    p[2] = (_Float16)(__expf(C[2]-MM.z)*ZZ.z); \
    p[3] = (_Float16)(__expf(C[3]-MM.w)*ZZ.w); \
    const int q_ = (QT)*16 + l15; \
    *(half4v*)((char*)(PT) + q_*128 + (sb2 ^ ((q_ & 7) << 4))) = p; \
} while(0)

#define ABODY(KA, KAN, VB, VBN, MM, ZZ, MMN, ZZN, PT) do { \
    f32x4 c0 = {0.f,0.f,0.f,0.f}, c1 = {0.f,0.f,0.f,0.f}; \
    f32x4 c2 = {0.f,0.f,0.f,0.f}, c3 = {0.f,0.f,0.f,0.f}; \
    c0 = MFMA16(KA[0], qb[0][0], c0); c0 = MFMA16(KA[1], qb[0][1], c0); \
    c1 = MFMA16(KA[0], qb[1][0], c1); c1 = MFMA16(KA[1], qb[1][1], c1); \
    c2 = MFMA16(KA[0], qb[2][0], c2); c2 = MFMA16(KA[1], qb[2][1], c2); \
    c3 = MFMA16(KA[0], qb[3][0], c3); c3 = MFMA16(KA[1], qb[3][1], c3); \
    KAN[0] = *(const half8*)(Kp); \
    KAN[1] = *(const half8*)(Kp + 1024); \
    Kp += 8192; \
    WRP(PT, 0, c0, MM, ZZ); WRP(PT, 1, c1, MM, ZZ); \
    WRP(PT, 2, c2, MM, ZZ); WRP(PT, 3, c3, MM, ZZ); \
    asm volatile("s_waitcnt lgkmcnt(0)\n\ts_barrier" ::: "memory"); \
    MMN = *(const float4*)Mp; Mp += 64; \
    ZZN = *(const float4*)Zp; Zp += 64; \
    _Pragma("unroll") \
    for (int d_ = 0; d_ < 4; ++d_){ \
        VBN[d_]   = *(const half8*)(Vp0 + d_*1024); \
        VBN[4+d_] = *(const half8*)(Vp1 + d_*1024); \
    } \
    Vp0 += 65536; Vp1 += 65536; \
    __builtin_amdgcn_s_setprio(1); \
    _Pragma("unroll") \
    for (int ks = 0; ks < 2; ++ks){ \
        const half8 pa0 = ldfrag(PT, 0*16 + l15, ks*4 + l4); \
        const half8 pa1 = ldfrag(PT, 1*16 + l15, ks*4 + l4); \
        const half8 pa2 = ldfrag(PT, 2*16 + l15, ks*4 + l4); \
        const half8 pa3 = ldfrag(PT, 3*16 + l15, ks*4 + l4); \
        _Pragma("unroll") \
        for (int d_ = 0; d_ < 4; ++d_){ \
            acc[0][d_] = MFMA16(pa0, VB[ks*4+d_], acc[0][d_]); \
            acc[1][d_] = MFMA16(pa1, VB[ks*4+d_], acc[1][d_]); \
            acc[2][d_] = MFMA16(pa2, VB[ks*4+d_], acc[2][d_]); \
            acc[3][d_] = MFMA16(pa3, VB[ks*4+d_], acc[3][d_]); \
        } \
    } \
    __builtin_amdgcn_s_setprio(0); \
} while(0)

__global__ __launch_bounds__(256, 2) void attn_kernel(
    const _Float16* __restrict__ Qh2, const _Float16* __restrict__ Kh2,
    const _Float16* __restrict__ Vt2, const float* __restrict__ Ms,
    const float* __restrict__ IZ, float* __restrict__ out)
{
    __shared__ _Float16 Pt[2][64*64];   // 16 KB
    const int bid = blockIdx.x;
    const int b  = bid & 7;             // b-major -> one batch per XCD
    const int qi = (bid >> 3) & 31;
    const int dh = bid >> 8;            // 0..1 d-half
    const int q0 = qi * 64;
    const int tid = threadIdx.x, lane = tid & 63, w = tid >> 6;   // w 0..3
    const int l15 = lane & 15, l4 = lane >> 4;
    const int soff = w*16 + l4*4;       // s offset within tile (wave owns s-tile w)
    const int sb2  = soff * 2;

    // Q fragments (held whole kernel)
    const size_t qgb = (size_t)b*128 + qi*4;
    half8 qb[4][2];
    #pragma unroll
    for (int qt = 0; qt < 4; ++qt)
        #pragma unroll
        for (int ks = 0; ks < 2; ++ks)
            qb[qt][ks] = *(const half8*)(Qh2 + (((qgb + qt)*2 + ks)*64 + lane)*8);

    // bumped pointers (point at next tile to fetch)
    const char* Kp  = (const char*)Kh2 + (size_t)(b*128 + w)*2048 + lane*16;
    const char* Vp0 = (const char*)Vt2 + (size_t)(b*2048 + dh*16 + w*4)*1024 + lane*16;
    const char* Vp1 = Vp0 + 32768;
    const float* Mp = Ms + b*Sn + soff;
    const float* Zp = IZ + b*Sn + soff;

    // prologue: prefetch sc=0
    half8 kaA[2], kaB[2], vbA[8], vbB[8];
    float4 mmA, zzA, mmB, zzB;
    kaA[0] = *(const half8*)(Kp);
    kaA[1] = *(const half8*)(Kp + 1024);
    Kp += 8192;
    #pragma unroll
    for (int d_ = 0; d_ < 4; ++d_){
        vbA[d_]   = *(const half8*)(Vp0 + d_*1024);
        vbA[4+d_] = *(const half8*)(Vp1 + d_*1024);
    }
    Vp0 += 65536; Vp1 += 65536;
    mmA = *(const float4*)Mp; Mp += 64;
    zzA = *(const float4*)Zp; Zp += 64;

    f32x4 acc[4][4];
    #pragma unroll
    for (int i = 0; i < 4; ++i)
        #pragma unroll
        for (int j = 0; j < 4; ++j){ f32x4 zz4 = {0.f,0.f,0.f,0.f}; acc[i][j] = zz4; }

    for (int it = 0; it < 16; ++it){
        ABODY(kaA, kaB, vbA, vbB, mmA, zzA, mmB, zzB, Pt[0]);
        ABODY(kaB, kaA, vbB, vbA, mmB, zzB, mmA, zzA, Pt[1]);
    }

    float* ob = out + (size_t)(b*Sn + q0)*Dn + dh*256 + w*64;
    #pragma unroll
    for (int qt = 0; qt < 4; ++qt){
        const int q = qt*16 + l4*4;
        #pragma unroll
        for (int d_ = 0; d_ < 4; ++d_){
            #pragma unroll
            for (int r = 0; r < 4; ++r)
                ob[(size_t)(q + r)*Dn + d_*16 + l15] = acc[qt][d_][r];
        }
    }
}

extern "C" void kernel_launch(void* const* d_in, const int* in_sizes, int n_in,
                              void* d_out, int out_size, void* d_ws, size_t ws_size,
                              hipStream_t stream)
{
    const float* X  = (const float*)d_in[0];
    const float* Wk = (const float*)d_in[1];
    const float* bk = (const float*)d_in[2];
    const float* Wq = (const float*)d_in[3];
    const float* bq = (const float*)d_in[4];
    float* out = (float*)d_out;

    char* ws = (char*)d_ws;
    _Float16* Qh2  = (_Float16*)ws;                                  // 2 MB
    _Float16* Kh2  = (_Float16*)(ws + ((size_t)2 << 20));            // 2 MB
    _Float16* Vt2  = (_Float16*)(ws + ((size_t)4 << 20));            // 16 MB
    float*    Ms   = (float*)(ws + ((size_t)20 << 20));              // 64 KB
    float*    IZ   = (float*)(ws + ((size_t)20 << 20) + (1 << 16));  // 64 KB
    _Float16* Wt16 = (_Float16*)(ws + ((size_t)20 << 20) + (2 << 16)); // 128 KB

    wtrans_kernel<<<dim3(128), dim3(256), 0, stream>>>(Wk, Wq, Wt16);
    prep_kernel<<<dim3(Bn*(Sn/32)), dim3(256), 0, stream>>>(X, Wt16, bk, bq, Qh2, Kh2, Vt2);
    stats_kernel<<<dim3(Bn*(Sn/64)), dim3(512), 0, stream>>>(Qh2, Kh2, Ms, IZ);
    attn_kernel<<<dim3(Bn*(Sn/64)*2), dim3(256), 0, stream>>>(Qh2, Kh2, Vt2, Ms, IZ, out);
}

// Round 6
// 82.290 us; speedup vs baseline: 1.7830x; 1.0564x over previous
//
#include <hip/hip_runtime.h>
#include <hip/hip_bf16.h>

#define Bn 8
#define Sn 2048
#define Dn 512
#define Kn 64

typedef _Float16 half8 __attribute__((ext_vector_type(8)));
typedef _Float16 half4v __attribute__((ext_vector_type(4)));
typedef float f32x4 __attribute__((ext_vector_type(4)));

#define MFMA16(a,b,c) __builtin_amdgcn_mfma_f32_16x16x32_f16(a,b,c,0,0,0)
#define LOG2E 1.4426950408889634f

// LDS tiles [rows][64] f16 (128B rows), XOR-swizzled on 16B granules.
__device__ __forceinline__ half8 ldfrag(const _Float16* base, int row, int k8){
    const int scol = k8 ^ (row & 7);
    return *(const half8*)((const char*)base + row*128 + scol*16);
}

// Fragment layouts in global memory (16B granules, lane = l4*16+l15):
//  Qh2/Kh2: granule (t*2+ks)*64+lane = M[t*16+l15][ks*32+l4*8 .. +8]   (t = global 16-row tile)
//  Vt2:     granule (((b*32+sc)*2+ks)*32+dt)*64+lane = V[dt*16+l15][sc*64+(ks*4+l4)*8 .. +8]
// Q is pre-scaled by log2(e): logits come out in base-2 domain.
// Stats:  z[s] = sum_q 2^(l2[q,s] - 64)  (fixed M0=64, no online max needed)
// CS[s] = -(64 + log2 z[s]);  attn:  P[q,s] = 2^(l2[q,s] + CS[s]) via MFMA C-init.

// ---- Kernel 0: W transpose+cast: Wt16[n][k], n<64 -> Wq col n, else Wk ----
__global__ __launch_bounds__(256) void wtrans_kernel(
    const float* __restrict__ Wk, const float* __restrict__ Wq,
    _Float16* __restrict__ Wt16)
{
    const int n = blockIdx.x;          // 0..127
    const int t = threadIdx.x;
    const float* src = (n < 64) ? Wq : Wk;
    const int nn = n & 63;
    #pragma unroll
    for (int i = 0; i < 2; ++i){
        const int k = t + 256*i;
        Wt16[(size_t)n*Dn + k] = (_Float16)src[(size_t)k*Kn + nn];
    }
}

// ---- Kernel 1: fused Q/K projection + V transpose (32 rows per block) ----
// Xt swizzle: granule phys = g ^ (row&7) ^ (row>>3)  (3-bit XOR)
__global__ __launch_bounds__(256, 2) void prep_kernel(
    const float* __restrict__ X, const _Float16* __restrict__ Wt16,
    const float* __restrict__ bk, const float* __restrict__ bq,
    _Float16* __restrict__ Qh2, _Float16* __restrict__ Kh2,
    _Float16* __restrict__ Vt2)
{
    __shared__ _Float16 Xt[2][32*64];   // 8 KB
    const int bid = blockIdx.x;
    const int b = bid & 7, sb32 = bid >> 3;     // b-major -> XCD locality
    const int tid = threadIdx.x, lane = tid & 63, w = tid >> 6;
    const int l15 = lane & 15, l4 = lane >> 4;

    // stage mapping: one half8 granule per thread per kc
    const int srow = tid >> 3, sg = tid & 7;
    const float* Xs = X + ((size_t)(b*Sn + sb32*32) + srow)*Dn + sg*8;
    const int sdst = srow*128 + (((sg ^ (srow & 7) ^ (srow >> 3)) & 7) * 16);

    // W fragment pointers (B-operand frags are contiguous 16B in Wt16)
    const int n0 = w*32 + l15;
    const _Float16* Wp0 = Wt16 + (size_t)n0*Dn + l4*8;
    const _Float16* Wp1 = Wp0 + (size_t)16*Dn;

    f32x4 acc[2][2];
    #pragma unroll
    for (int i = 0; i < 2; ++i)
        #pragma unroll
        for (int j = 0; j < 2; ++j){ f32x4 z = {0.f,0.f,0.f,0.f}; acc[i][j] = z; }

    // prologue: stage kc=0
    {
        const float4 v0 = *(const float4*)(Xs);
        const float4 v1 = *(const float4*)(Xs + 4);
        half8 h;
        h[0]=(_Float16)v0.x; h[1]=(_Float16)v0.y; h[2]=(_Float16)v0.z; h[3]=(_Float16)v0.w;
        h[4]=(_Float16)v1.x; h[5]=(_Float16)v1.y; h[6]=(_Float16)v1.z; h[7]=(_Float16)v1.w;
        *(half8*)((char*)Xt[0] + sdst) = h;
    }
    __syncthreads();

    const int dcol = w*16 + l15;     // V-emit column (d within kc chunk)
    #pragma unroll
    for (int kc = 0; kc < 8; ++kc){
        const _Float16* XtC = Xt[kc & 1];
        float4 nv0, nv1;
        if (kc < 7){
            nv0 = *(const float4*)(Xs + (kc+1)*64);
            nv1 = *(const float4*)(Xs + (kc+1)*64 + 4);
        }
        const half8 wf00 = *(const half8*)(Wp0 + kc*64);
        const half8 wf01 = *(const half8*)(Wp0 + kc*64 + 32);
        const half8 wf10 = *(const half8*)(Wp1 + kc*64);
        const half8 wf11 = *(const half8*)(Wp1 + kc*64 + 32);
        #pragma unroll
        for (int ks = 0; ks < 2; ++ks){
            #pragma unroll
            for (int qt = 0; qt < 2; ++qt){
                const int rw = qt*16 + l15;
                const int g = ((ks*4 + l4) ^ (rw & 7) ^ (rw >> 3)) & 7;
                const half8 a = *(const half8*)((const char*)XtC + rw*128 + g*16);
                acc[qt][0] = MFMA16(a, ks ? wf01 : wf00, acc[qt][0]);
                acc[qt][1] = MFMA16(a, ks ? wf11 : wf10, acc[qt][1]);
            }
        }
        // V-emit: one Vt2 granule per thread (conflict-free column gather)
        {
            half8 hv;
            #pragma unroll
            for (int e = 0; e < 8; ++e){
                const int rw = l4*8 + e;
                const int g = ((dcol >> 3) ^ e ^ l4) & 7;
                hv[e] = XtC[rw*64 + g*8 + (dcol & 7)];
            }
            const size_t G = (((size_t)(b*32 + (sb32 >> 1))*2 + (sb32 & 1))*32 + kc*4 + w)*64 + lane;
            *(half8*)(Vt2 + G*8) = hv;
        }
        if (kc < 7){
            half8 h;
            h[0]=(_Float16)nv0.x; h[1]=(_Float16)nv0.y; h[2]=(_Float16)nv0.z; h[3]=(_Float16)nv0.w;
            h[4]=(_Float16)nv1.x; h[5]=(_Float16)nv1.y; h[6]=(_Float16)nv1.z; h[7]=(_Float16)nv1.w;
            *(half8*)((char*)Xt[(kc+1) & 1] + sdst) = h;
        }
        __syncthreads();
    }

    // epilogue: bias (+log2e scale for Q) + pack [32 q][128 n] + fragment stores
    _Float16* tile16 = &Xt[0][0];   // 8 KB, stride 128
    #pragma unroll
    for (int qt = 0; qt < 2; ++qt){
        const int ql = qt*16 + l4*4;
        #pragma unroll
        for (int nt = 0; nt < 2; ++nt){
            const int n = w*32 + nt*16 + l15;
            const bool isQ = (n < 64);
            const float bias = isQ ? bq[n] : bk[n - 64];
            const float scale = isQ ? LOG2E : 1.0f;
            #pragma unroll
            for (int r = 0; r < 4; ++r)
                tile16[(ql + r)*128 + n] = (_Float16)((acc[qt][nt][r] + bias) * scale);
        }
    }
    __syncthreads();
    #pragma unroll
    for (int i = 0; i < 2; ++i){
        const int g = tid + 256*i;          // 0..511
        const int isK = g >> 8, qtl = (g >> 7) & 1, ks = (g >> 6) & 1, ln = g & 63;
        const int l4g = ln >> 4, l15g = ln & 15;
        const half8 h = *(const half8*)&tile16[(qtl*16 + l15g)*128 + isK*64 + ks*32 + l4g*8];
        const size_t tg = (size_t)b*128 + sb32*2 + qtl;
        _Float16* dst = (isK ? Kh2 : Qh2) + ((tg*2 + ks)*64 + ln)*8;
        *(half8*)dst = h;
    }
}

// ---- Kernel 2: per-(b,s) column denominators (base-2, fixed M0=64) ----
#define SBODY(QC0,QC1,QC2,QC3, QN0,QN1,QN2,QN3) do { \
    QN0 = *(const half8*)(Qp); \
    QN1 = *(const half8*)(Qp + 1024); \
    QN2 = *(const half8*)(Qp + 2048); \
    QN3 = *(const half8*)(Qp + 3072); \
    Qp += 8192; \
    f32x4 c0 = cinit, c1 = cinit; \
    c0 = MFMA16(ka0, QC0, c0); c0 = MFMA16(ka1, QC1, c0); \
    c1 = MFMA16(ka0, QC2, c1); c1 = MFMA16(ka1, QC3, c1); \
    _Pragma("unroll") \
    for (int r = 0; r < 4; ++r) \
        z[r] += exp2f(c0[r]) + exp2f(c1[r]); \
} while(0)

__global__ __launch_bounds__(512, 2) void stats_kernel(
    const _Float16* __restrict__ Qh2, const _Float16* __restrict__ Kh2,
    float* __restrict__ CS)
{
    __shared__ float zred[2][64];
    const int bid = blockIdx.x;
    const int b = bid & 7, stb = bid >> 3;
    const int tid = threadIdx.x, lane = tid & 63, w = tid >> 6;
    const int l15 = lane & 15, l4 = lane >> 4;
    const int sw = w & 3, qh = w >> 2, qh2 = qh*2;

    const half8 ka0 = *(const half8*)(Kh2 + ((size_t)((b*128 + stb*4 + sw)*2 + 0)*64 + lane)*8);
    const half8 ka1 = *(const half8*)(Kh2 + ((size_t)((b*128 + stb*4 + sw)*2 + 1)*64 + lane)*8);

    const char* Qp = (const char*)Qh2 + (size_t)(b*128 + qh2)*2048 + lane*16;

    const f32x4 cinit = {-64.f, -64.f, -64.f, -64.f};
    float z[4] = {0.f, 0.f, 0.f, 0.f};

    half8 qbA0, qbA1, qbA2, qbA3, qbB0, qbB1, qbB2, qbB3;
    qbA0 = *(const half8*)(Qp);
    qbA1 = *(const half8*)(Qp + 1024);
    qbA2 = *(const half8*)(Qp + 2048);
    qbA3 = *(const half8*)(Qp + 3072);
    Qp += 8192;

    for (int qc = 0; qc < 32; qc += 2){
        SBODY(qbA0,qbA1,qbA2,qbA3, qbB0,qbB1,qbB2,qbB3);
        SBODY(qbB0,qbB1,qbB2,qbB3, qbA0,qbA1,qbA2,qbA3);
    }
    // sum over the 16 q-columns held across lanes (l15 dim)
    #pragma unroll
    for (int d = 1; d < 16; d <<= 1)
        #pragma unroll
        for (int r = 0; r < 4; ++r)
            z[r] += __shfl_xor(z[r], d);
    if (l15 == 0){
        const int sl = sw*16 + l4*4;
        #pragma unroll
        for (int r = 0; r < 4; ++r) zred[qh][sl+r] = z[r];
    }
    __syncthreads();
    if (tid < 64)
        CS[b*Sn + stb*64 + tid] = -(64.0f + __log2f(zred[0][tid] + zred[1][tid]));
}

// ---- Kernel 3: fused logits -> P -> P@V; 4-wave 64q x 256d blocks ----
#define WRP(PT, QT, C) do { \
    half4v p; \
    p[0] = (_Float16)exp2f(C[0]); \
    p[1] = (_Float16)exp2f(C[1]); \
    p[2] = (_Float16)exp2f(C[2]); \
    p[3] = (_Float16)exp2f(C[3]); \
    const int q_ = (QT)*16 + l15; \
    *(half4v*)((char*)(PT) + q_*128 + (sb2 ^ ((q_ & 7) << 4))) = p; \
} while(0)

#define ABODY(KA, KAN, VB, VBN, CSV, CSN, PT) do { \
    f32x4 c0 = {CSV.x, CSV.y, CSV.z, CSV.w}; \
    f32x4 c1 = c0, c2 = c0, c3 = c0; \
    c0 = MFMA16(KA[0], qb[0][0], c0); c0 = MFMA16(KA[1], qb[0][1], c0); \
    c1 = MFMA16(KA[0], qb[1][0], c1); c1 = MFMA16(KA[1], qb[1][1], c1); \
    c2 = MFMA16(KA[0], qb[2][0], c2); c2 = MFMA16(KA[1], qb[2][1], c2); \
    c3 = MFMA16(KA[0], qb[3][0], c3); c3 = MFMA16(KA[1], qb[3][1], c3); \
    KAN[0] = *(const half8*)(Kp); \
    KAN[1] = *(const half8*)(Kp + 1024); \
    Kp += 8192; \
    WRP(PT, 0, c0); WRP(PT, 1, c1); \
    WRP(PT, 2, c2); WRP(PT, 3, c3); \
    asm volatile("s_waitcnt lgkmcnt(0)\n\ts_barrier" ::: "memory"); \
    CSN = *(const float4*)Cp; Cp += 64; \
    _Pragma("unroll") \
    for (int d_ = 0; d_ < 4; ++d_){ \
        VBN[d_]   = *(const half8*)(Vp0 + d_*1024); \
        VBN[4+d_] = *(const half8*)(Vp1 + d_*1024); \
    } \
    Vp0 += 65536; Vp1 += 65536; \
    __builtin_amdgcn_s_setprio(1); \
    _Pragma("unroll") \
    for (int ks = 0; ks < 2; ++ks){ \
        const half8 pa0 = ldfrag(PT, 0*16 + l15, ks*4 + l4); \
        const half8 pa1 = ldfrag(PT, 1*16 + l15, ks*4 + l4); \
        const half8 pa2 = ldfrag(PT, 2*16 + l15, ks*4 + l4); \
        const half8 pa3 = ldfrag(PT, 3*16 + l15, ks*4 + l4); \
        _Pragma("unroll") \
        for (int d_ = 0; d_ < 4; ++d_){ \
            acc[0][d_] = MFMA16(pa0, VB[ks*4+d_], acc[0][d_]); \
            acc[1][d_] = MFMA16(pa1, VB[ks*4+d_], acc[1][d_]); \
            acc[2][d_] = MFMA16(pa2, VB[ks*4+d_], acc[2][d_]); \
            acc[3][d_] = MFMA16(pa3, VB[ks*4+d_], acc[3][d_]); \
        } \
    } \
    __builtin_amdgcn_s_setprio(0); \
} while(0)

__global__ __launch_bounds__(256, 2) void attn_kernel(
    const _Float16* __restrict__ Qh2, const _Float16* __restrict__ Kh2,
    const _Float16* __restrict__ Vt2, const float* __restrict__ CS,
    float* __restrict__ out)
{
    __shared__ _Float16 Pt[2][64*64];   // 16 KB
    const int bid = blockIdx.x;
    const int b  = bid & 7;             // b-major -> one batch per XCD
    const int qi = (bid >> 3) & 31;
    const int dh = bid >> 8;            // 0..1 d-half
    const int q0 = qi * 64;
    const int tid = threadIdx.x, lane = tid & 63, w = tid >> 6;   // w 0..3
    const int l15 = lane & 15, l4 = lane >> 4;
    const int soff = w*16 + l4*4;       // s offset within tile (wave owns s-tile w)
    const int sb2  = soff * 2;

    // Q fragments (held whole kernel)
    const size_t qgb = (size_t)b*128 + qi*4;
    half8 qb[4][2];
    #pragma unroll
    for (int qt = 0; qt < 4; ++qt)
        #pragma unroll
        for (int ks = 0; ks < 2; ++ks)
            qb[qt][ks] = *(const half8*)(Qh2 + (((qgb + qt)*2 + ks)*64 + lane)*8);

    // bumped pointers (point at next tile to fetch)
    const char* Kp  = (const char*)Kh2 + (size_t)(b*128 + w)*2048 + lane*16;
    const char* Vp0 = (const char*)Vt2 + (size_t)(b*2048 + dh*16 + w*4)*1024 + lane*16;
    const char* Vp1 = Vp0 + 32768;
    const float* Cp = CS + b*Sn + soff;

    // prologue: prefetch sc=0
    half8 kaA[2], kaB[2], vbA[8], vbB[8];
    float4 csA, csB;
    kaA[0] = *(const half8*)(Kp);
    kaA[1] = *(const half8*)(Kp + 1024);
    Kp += 8192;
    #pragma unroll
    for (int d_ = 0; d_ < 4; ++d_){
        vbA[d_]   = *(const half8*)(Vp0 + d_*1024);
        vbA[4+d_] = *(const half8*)(Vp1 + d_*1024);
    }
    Vp0 += 65536; Vp1 += 65536;
    csA = *(const float4*)Cp; Cp += 64;

    f32x4 acc[4][4];
    #pragma unroll
    for (int i = 0; i < 4; ++i)
        #pragma unroll
        for (int j = 0; j < 4; ++j){ f32x4 zz4 = {0.f,0.f,0.f,0.f}; acc[i][j] = zz4; }

    for (int it = 0; it < 16; ++it){
        ABODY(kaA, kaB, vbA, vbB, csA, csB, Pt[0]);
        ABODY(kaB, kaA, vbB, vbA, csB, csA, Pt[1]);
    }

    float* ob = out + (size_t)(b*Sn + q0)*Dn + dh*256 + w*64;
    #pragma unroll
    for (int qt = 0; qt < 4; ++qt){
        const int q = qt*16 + l4*4;
        #pragma unroll
        for (int d_ = 0; d_ < 4; ++d_){
            #pragma unroll
            for (int r = 0; r < 4; ++r)
                ob[(size_t)(q + r)*Dn + d_*16 + l15] = acc[qt][d_][r];
        }
    }
}

extern "C" void kernel_launch(void* const* d_in, const int* in_sizes, int n_in,
                              void* d_out, int out_size, void* d_ws, size_t ws_size,
                              hipStream_t stream)
{
    const float* X  = (const float*)d_in[0];
    const float* Wk = (const float*)d_in[1];
    const float* bk = (const float*)d_in[2];
    const float* Wq = (const float*)d_in[3];
    const float* bq = (const float*)d_in[4];
    float* out = (float*)d_out;

    char* ws = (char*)d_ws;
    _Float16* Qh2  = (_Float16*)ws;                                  // 2 MB
    _Float16* Kh2  = (_Float16*)(ws + ((size_t)2 << 20));            // 2 MB
    _Float16* Vt2  = (_Float16*)(ws + ((size_t)4 << 20));            // 16 MB
    float*    CS   = (float*)(ws + ((size_t)20 << 20));              // 64 KB (+64 KB guard)
    _Float16* Wt16 = (_Float16*)(ws + ((size_t)20 << 20) + (2 << 16)); // 128 KB

    wtrans_kernel<<<dim3(128), dim3(256), 0, stream>>>(Wk, Wq, Wt16);
    prep_kernel<<<dim3(Bn*(Sn/32)), dim3(256), 0, stream>>>(X, Wt16, bk, bq, Qh2, Kh2, Vt2);
    stats_kernel<<<dim3(Bn*(Sn/64)), dim3(512), 0, stream>>>(Qh2, Kh2, CS);
    attn_kernel<<<dim3(Bn*(Sn/64)*2), dim3(256), 0, stream>>>(Qh2, Kh2, Vt2, CS, out);
}